// Round 14
// baseline (214.258 us; speedup 1.0000x reference)
//
#include <hip/hip_runtime.h>
#include <hip/hip_bf16.h>

// Problem: B=2, N=4096, QD=512, HEADS=8, DIM_HEAD=64, INNER=512
// softmax scale 1/8 AND log2(e) folded into Q: P = exp2(S').

typedef __attribute__((ext_vector_type(8))) short short8;
typedef __attribute__((ext_vector_type(4))) float floatx4;

#define MFMA16(a, b, c) __builtin_amdgcn_mfma_f32_16x16x32_bf16((a), (b), (c), 0, 0, 0)

#if __has_builtin(__builtin_amdgcn_exp2f)
#define EXP2(x) __builtin_amdgcn_exp2f(x)
#else
#define EXP2(x) exp2f(x)
#endif

// (1/8) * log2(e)
#define QSCALE 0.18033688011112042f

// fp32 -> bf16 (round-to-nearest-even)
static __device__ __forceinline__ unsigned short f2b(float f) {
  unsigned int u = __float_as_uint(f);
  u += 0x7FFFu + ((u >> 16) & 1u);
  return (unsigned short)(u >> 16);
}

// packed pair fp32 -> 2x bf16 in one u32
static __device__ __forceinline__ unsigned int pkb(float a, float b) {
  float2 t{a, b};
  __hip_bfloat162 h = __float22bfloat162_rn(t);
  union { __hip_bfloat162 h2; unsigned int u; } cv;
  cv.h2 = h;
  return cv.u;
}

// async global->LDS DMA: 16 B/lane; dest = wave-uniform base + lane*16.
static __device__ __forceinline__ void dma16(const unsigned short* g,
                                             unsigned short* l) {
  __builtin_amdgcn_global_load_lds(
      (const __attribute__((address_space(1))) unsigned int*)g,
      (__attribute__((address_space(3))) unsigned int*)l, 16, 0, 0);
}

// ---------------------------------------------------------------------------
// Kernel 0: prep — VERBATIM R12/R13.
// ---------------------------------------------------------------------------
__global__ __launch_bounds__(256) void prep_kernel(
    const float* __restrict__ Wq, const float* __restrict__ Wk,
    const float* __restrict__ Wv, const float* __restrict__ Wo,
    const float* __restrict__ x, unsigned short* __restrict__ wtq,
    unsigned short* __restrict__ wtk, unsigned short* __restrict__ wtv,
    unsigned short* __restrict__ wto, unsigned short* __restrict__ xb) {
  const int z = blockIdx.z;
  const int tid = threadIdx.x;
  if (z >= 4) {
    const int bid = (z - 4) * 256 + blockIdx.y * 16 + blockIdx.x;
    const int idx = (bid * 256 + tid) * 8;
    const float4 a = *(const float4*)(x + idx);
    const float4 b = *(const float4*)(x + idx + 4);
    unsigned int u[4] = {pkb(a.x, a.y), pkb(a.z, a.w), pkb(b.x, b.y),
                         pkb(b.z, b.w)};
    *(short8*)(xb + idx) = *(short8*)u;
    return;
  }
  const float* __restrict__ W = (z == 0) ? Wq : (z == 1) ? Wk : (z == 2) ? Wv : Wo;
  unsigned short* __restrict__ T = (z == 0) ? wtq : (z == 1) ? wtk : (z == 2) ? wtv : wto;
  const int k0 = blockIdx.x * 32, c0 = blockIdx.y * 32;
  __shared__ float Ts[32][33];
  const int r = tid >> 3, cc = (tid & 7) * 4;
  const float4 v = *(const float4*)(W + (k0 + r) * 512 + c0 + cc);
  Ts[r][cc] = v.x; Ts[r][cc + 1] = v.y; Ts[r][cc + 2] = v.z; Ts[r][cc + 3] = v.w;
  __syncthreads();
  const unsigned long long uu =
      (unsigned long long)pkb(Ts[cc][r], Ts[cc + 1][r]) |
      ((unsigned long long)pkb(Ts[cc + 2][r], Ts[cc + 3][r]) << 32);
  *(unsigned long long*)(T + (c0 + r) * 512 + k0 + cc) = uu;
}

// ---------------------------------------------------------------------------
// Kernel 1: fused QKV — VERBATIM R13 (all-DMA dbuf, M=128 N=32/z, BK=64).
// ---------------------------------------------------------------------------
__global__ __launch_bounds__(256) void qkv_fused_kernel(
    const unsigned short* __restrict__ xb, const unsigned short* __restrict__ wtq,
    const unsigned short* __restrict__ wtk,
    const unsigned short* __restrict__ wtv, unsigned short* __restrict__ qo,
    unsigned short* __restrict__ ko, unsigned short* __restrict__ vo) {
  const int m0 = blockIdx.x * 128;  // 64
  const int c0 = blockIdx.y * 32;   // 16
  __shared__ __align__(16) unsigned short As[2][128 * 64];    // 32 KB
  __shared__ __align__(16) unsigned short Bs[2][3][32 * 64];  // 24 KB
  const int tid = threadIdx.x;
  const int lane = tid & 63, w = tid >> 6;
  const int i = lane & 15, q = lane >> 4;
  const int sl = i & 7;
  const int dr = lane >> 3, dc = lane & 7;
  const int sch = (dc ^ dr) * 8;
  const unsigned short* ag = xb + (m0 + w * 32 + dr) * 512 + sch;
  const unsigned short* bg[3];
  bg[0] = wtq + (c0 + w * 8 + dr) * 512 + sch;
  bg[1] = wtk + (c0 + w * 8 + dr) * 512 + sch;
  bg[2] = wtv + (c0 + w * 8 + dr) * 512 + sch;

  floatx4 acc[3][2][2] = {};

#pragma unroll
  for (int p = 0; p < 4; ++p) dma16(ag + p * 8 * 512, &As[0][(w * 32 + p * 8) * 64]);
#pragma unroll
  for (int z = 0; z < 3; ++z) dma16(bg[z], &Bs[0][z][(w * 8) * 64]);
  __syncthreads();

  int buf = 0;
  for (int ks = 0; ks < 8; ++ks) {
    if (ks < 7) {
      const int k1 = (ks + 1) * 64;
#pragma unroll
      for (int p = 0; p < 4; ++p)
        dma16(ag + p * 8 * 512 + k1, &As[buf ^ 1][(w * 32 + p * 8) * 64]);
#pragma unroll
      for (int z = 0; z < 3; ++z)
        dma16(bg[z] + k1, &Bs[buf ^ 1][z][(w * 8) * 64]);
    }
#pragma unroll
    for (int kc = 0; kc < 2; ++kc) {
      short8 af[2];
#pragma unroll
      for (int t = 0; t < 2; ++t)
        af[t] = *(const short8*)&As[buf][(w * 32 + t * 16 + i) * 64 +
                                        (((kc * 4 + q) ^ sl) * 8)];
#pragma unroll
      for (int z = 0; z < 3; ++z)
#pragma unroll
        for (int g = 0; g < 2; ++g) {
          const short8 bf = *(const short8*)&Bs[buf][z][(g * 16 + i) * 64 +
                                                        (((kc * 4 + q) ^ sl) * 8)];
#pragma unroll
          for (int t = 0; t < 2; ++t)
            acc[z][t][g] = MFMA16(af[t], bf, acc[z][t][g]);
        }
    }
    __syncthreads();
    buf ^= 1;
  }
#pragma unroll
  for (int z = 0; z < 3; ++z)
#pragma unroll
    for (int t = 0; t < 2; ++t)
#pragma unroll
      for (int g = 0; g < 2; ++g) {
        const int col = c0 + g * 16 + i;
        const int h = col >> 6, d = col & 63;
        const int row0 = m0 + w * 32 + t * 16 + q * 4;
        const int b = row0 >> 12;
        const int n0 = row0 & 4095;
        if (z == 2) {
          unsigned int* dst =
              (unsigned int*)&vo[(((b * 8 + h) * 64 + d) << 12) + n0];
          dst[0] = pkb(acc[z][t][g][0], acc[z][t][g][1]);
          dst[1] = pkb(acc[z][t][g][2], acc[z][t][g][3]);
        } else {
          unsigned short* dst = (z == 0) ? qo : ko;
          const float sc = (z == 0) ? QSCALE : 1.0f;
#pragma unroll
          for (int r = 0; r < 4; ++r)
            dst[(((b * 8 + h) << 12) + (n0 + r)) * 64 + d] =
                f2b(acc[z][t][g][r] * sc);
        }
      }
}

// ---------------------------------------------------------------------------
// Kernel 2: flash attention — 64 Q-rows/WAVE (R8 idea, spill-safe redo).
// 256 threads = 4 waves = 2 row-halves x 2 key groups; 128 rows/block.
// kf/vf fragments amortized over 4 m-tiles: 0.625 KB LDS/MFMA vs R7's 0.78.
// __launch_bounds__(256,2): cap 256 regs (peak ~190, NO spill — R8 died at
// cap 128).  LDS 64 KB -> 2 blocks/CU (LDS-capped, so the relaxed reg bound
// is free).  All layouts/swizzles/grid = R7-verified, t extended to 0..3;
// VALU row-sums (R9-verified) replace the ones-MFMA.  K/V single-buffered,
// 2 barriers/tile, register prefetch — the R7 schedule.
// ---------------------------------------------------------------------------
__global__ __launch_bounds__(256, 2) void flash_kernel(
    const unsigned short* __restrict__ Q, const unsigned short* __restrict__ K,
    const unsigned short* __restrict__ Vt, unsigned short* __restrict__ O) {
  const int bh = blockIdx.x;        // 16 (low grid bits: L2 locality, R9 lesson)
  const int m0 = blockIdx.y * 128;  // 32
  const int tid = threadIdx.x;
  const int lane = tid & 63, w = tid >> 6;
  const int i = lane & 15, q = lane >> 4;
  const int kg = w & 1;   // key group (2048 keys)
  const int rh = w >> 1;  // row half (64 rows)
  const int sl = i & 7;
  const unsigned short* qp = Q + bh * (4096 * 64);
  const unsigned short* kp = K + bh * (4096 * 64);
  const unsigned short* vp = Vt + bh * (64 * 4096);

  __shared__ __align__(16) unsigned short SM[32768];  // 64 KB
  unsigned short* Ks = SM + kg * 4096;          // [64 keys][64 d], swizzled
  unsigned short* Vs = SM + 8192 + kg * 4096;   // [64 d][64 keys], swizzled
  unsigned short* pw = SM + 16384 + w * 4096;   // per-wave P [64][64], swizzled

  // staging: kg's 128 threads cover its 64x64 K tile and V^T tile;
  // thread -> row s128>>1, chunks (s128&1)*4 + p (p=0..3), phys = c ^ (row&7)
  const int s128 = rh * 64 + lane;
  const int srow = s128 >> 1;
  const int sc0 = (s128 & 1) * 4;
  const unsigned short* kgp = kp + (kg * 2048 + srow) * 64 + sc0 * 8;
  const unsigned short* vgp = vp + srow * 4096 + kg * 2048 + sc0 * 8;
  int kvo[4];
#pragma unroll
  for (int p = 0; p < 4; ++p)
    kvo[p] = srow * 64 + (((sc0 + p) ^ (srow & 7)) * 8);

  // persistent Q fragments: rows m0 + rh*64 + t*16 + i, t = 0..3
  short8 qf[4][2];
#pragma unroll
  for (int t = 0; t < 4; ++t)
#pragma unroll
    for (int kc = 0; kc < 2; ++kc)
      qf[t][kc] = *(const short8*)(qp + (m0 + rh * 64 + t * 16 + i) * 64 +
                                   kc * 32 + q * 8);

  floatx4 accO[4][4] = {};
  float Lacc[4] = {0.f, 0.f, 0.f, 0.f};
  const floatx4 zf = {0.f, 0.f, 0.f, 0.f};

  // stage tile 0 of this key group
#pragma unroll
  for (int p = 0; p < 4; ++p) {
    *(short8*)&Ks[kvo[p]] = *(const short8*)(kgp + p * 8);
    *(short8*)&Vs[kvo[p]] = *(const short8*)(vgp + p * 8);
  }
  __syncthreads();

  for (int jt = 0; jt < 32; ++jt) {
    // prefetch next tile into registers (latency hidden by compute)
    short8 kn[4], vn[4];
    if (jt < 31) {
#pragma unroll
      for (int p = 0; p < 4; ++p) {
        kn[p] = *(const short8*)(kgp + (jt + 1) * 4096 + p * 8);
        vn[p] = *(const short8*)(vgp + (jt + 1) * 64 + p * 8);
      }
    }
    // QK^T (operand-swapped) + exp2 + P store; kf shared across 4 m-tiles
#pragma unroll
    for (int g = 0; g < 4; ++g) {
      const short8 kf0 = *(const short8*)(&Ks[(g * 16 + i) * 64 + (q ^ sl) * 8]);
      const short8 kf1 =
          *(const short8*)(&Ks[(g * 16 + i) * 64 + ((4 + q) ^ sl) * 8]);
#pragma unroll
      for (int t = 0; t < 4; ++t) {
        floatx4 s = MFMA16(kf0, qf[t][0], zf);
        s = MFMA16(kf1, qf[t][1], s);
        const float e0 = EXP2(s[0]), e1 = EXP2(s[1]);
        const float e2 = EXP2(s[2]), e3 = EXP2(s[3]);
        Lacc[t] += (e0 + e1) + (e2 + e3);
        *(unsigned long long*)&pw[(t * 16 + i) * 64 +
                                  (((2 * g + (q >> 1)) ^ sl) * 8) +
                                  (q & 1) * 4] =
            (unsigned long long)pkb(e0, e1) |
            ((unsigned long long)pkb(e2, e3) << 32);
      }
    }
    // P back as A-fragments (same-wave LDS dep; in-order DS pipe)
    short8 pf[4][2];
#pragma unroll
    for (int t = 0; t < 4; ++t) {
      pf[t][0] = *(const short8*)(pw + (t * 16 + i) * 64 + (q ^ sl) * 8);
      pf[t][1] = *(const short8*)(pw + (t * 16 + i) * 64 + ((4 + q) ^ sl) * 8);
    }
    // PV: vf shared across 4 m-tiles
#pragma unroll
    for (int dg = 0; dg < 4; ++dg) {
      const short8 vf0 =
          *(const short8*)(&Vs[(dg * 16 + i) * 64 + (q ^ sl) * 8]);
      const short8 vf1 =
          *(const short8*)(&Vs[(dg * 16 + i) * 64 + ((4 + q) ^ sl) * 8]);
#pragma unroll
      for (int t = 0; t < 4; ++t) {
        accO[t][dg] = MFMA16(pf[t][0], vf0, accO[t][dg]);
        accO[t][dg] = MFMA16(pf[t][1], vf1, accO[t][dg]);
      }
    }
    __syncthreads();  // all waves done reading this tile
    if (jt < 31) {
#pragma unroll
      for (int p = 0; p < 4; ++p) {
        *(short8*)&Ks[kvo[p]] = kn[p];
        *(short8*)&Vs[kvo[p]] = vn[p];
      }
    }
    __syncthreads();  // next tile published
  }

  // full row sums (uniform across q-lane groups) — R9-verified
#pragma unroll
  for (int t = 0; t < 4; ++t) {
    Lacc[t] += __shfl_xor(Lacc[t], 16);
    Lacc[t] += __shfl_xor(Lacc[t], 32);
  }
  // merge the two key groups (plain add; no rescale needed)
  float* MB = (float*)SM;  // [2][64][68] floats = 34.8 KB (K/V/P dead)
  if (kg == 1) {
    float* dst = MB + (rh * 64 + lane) * 68;
#pragma unroll
    for (int t = 0; t < 4; ++t) {
#pragma unroll
      for (int dg = 0; dg < 4; ++dg)
#pragma unroll
        for (int r = 0; r < 4; ++r) dst[t * 16 + dg * 4 + r] = accO[t][dg][r];
      dst[64 + t] = Lacc[t];
    }
  }
  __syncthreads();
  if (kg == 1) return;
  {
    const float* src = MB + (rh * 64 + lane) * 68;
#pragma unroll
    for (int t = 0; t < 4; ++t) {
#pragma unroll
      for (int dg = 0; dg < 4; ++dg)
#pragma unroll
        for (int r = 0; r < 4; ++r) accO[t][dg][r] += src[t * 16 + dg * 4 + r];
      Lacc[t] += src[64 + t];
    }
  }

  // epilogue: redistribute row-sums via shfl (R9-verified), normalize, store
  const int b = bh >> 3, h = bh & 7;
#pragma unroll
  for (int t = 0; t < 4; ++t) {
    float inv[4];
#pragma unroll
    for (int r = 0; r < 4; ++r) {
      const float l = __shfl(Lacc[t], (lane & 48) | (q * 4 + r), 64);
      inv[r] = 1.0f / l;
    }
#pragma unroll
    for (int dg = 0; dg < 4; ++dg)
#pragma unroll
      for (int r = 0; r < 4; ++r) {
        const int n = m0 + rh * 64 + t * 16 + q * 4 + r;
        const int col = h * 64 + dg * 16 + i;
        O[((b << 12) + n) * 512 + col] = f2b(accO[t][dg][r] * inv[r]);
      }
  }
}

// ---------------------------------------------------------------------------
// Kernel 3: out projection — VERBATIM R13 (all-DMA dbuf, 64x64, BK=64).
// ---------------------------------------------------------------------------
__global__ __launch_bounds__(256) void out_proj_kernel(
    const unsigned short* __restrict__ A, const unsigned short* __restrict__ wto,
    const float* __restrict__ bo, float* __restrict__ out) {
  const int m0 = blockIdx.x * 64, c0 = blockIdx.y * 64;
  __shared__ __align__(16) unsigned short As[2][64 * 64];  // 16 KB
  __shared__ __align__(16) unsigned short Bs[2][64 * 64];  // 16 KB
  const int tid = threadIdx.x;
  const int lane = tid & 63, w = tid >> 6;
  const int i = lane & 15, q = lane >> 4;
  const int wy = w >> 1, wx = w & 1;
  const int sl = i & 7;
  const int dr = lane >> 3, dc = lane & 7;
  const int sch = (dc ^ dr) * 8;
  const unsigned short* ag = A + (m0 + w * 16 + dr) * 512 + sch;
  const unsigned short* bg = wto + (c0 + w * 16 + dr) * 512 + sch;

  floatx4 acc[2][2] = {};
#pragma unroll
  for (int p = 0; p < 2; ++p) {
    dma16(ag + p * 8 * 512, &As[0][(w * 16 + p * 8) * 64]);
    dma16(bg + p * 8 * 512, &Bs[0][(w * 16 + p * 8) * 64]);
  }
  __syncthreads();

  int buf = 0;
  for (int ks = 0; ks < 8; ++ks) {
    if (ks < 7) {
      const int k1 = (ks + 1) * 64;
#pragma unroll
      for (int p = 0; p < 2; ++p) {
        dma16(ag + p * 8 * 512 + k1, &As[buf ^ 1][(w * 16 + p * 8) * 64]);
        dma16(bg + p * 8 * 512 + k1, &Bs[buf ^ 1][(w * 16 + p * 8) * 64]);
      }
    }
#pragma unroll
    for (int kc = 0; kc < 2; ++kc) {
      short8 af[2], bfr[2];
#pragma unroll
      for (int t = 0; t < 2; ++t)
        af[t] = *(const short8*)&As[buf][(wy * 32 + t * 16 + i) * 64 +
                                        (((kc * 4 + q) ^ sl) * 8)];
#pragma unroll
      for (int g = 0; g < 2; ++g)
        bfr[g] = *(const short8*)&Bs[buf][(wx * 32 + g * 16 + i) * 64 +
                                          (((kc * 4 + q) ^ sl) * 8)];
#pragma unroll
      for (int t = 0; t < 2; ++t)
#pragma unroll
        for (int g = 0; g < 2; ++g) acc[t][g] = MFMA16(af[t], bfr[g], acc[t][g]);
    }
    __syncthreads();
    buf ^= 1;
  }
#pragma unroll
  for (int t = 0; t < 2; ++t)
#pragma unroll
    for (int g = 0; g < 2; ++g) {
      const int col = c0 + wx * 32 + g * 16 + i;
      const float bias = bo[col];
#pragma unroll
      for (int r = 0; r < 4; ++r) {
        const int row = m0 + wy * 32 + t * 16 + q * 4 + r;
        out[row * 512 + col] = acc[t][g][r] + bias;
      }
    }
}

// ---------------------------------------------------------------------------
extern "C" void kernel_launch(void* const* d_in, const int* in_sizes, int n_in,
                              void* d_out, int out_size, void* d_ws,
                              size_t ws_size, hipStream_t stream) {
  const float* x = (const float*)d_in[0];
  const float* Wq = (const float*)d_in[1];
  const float* Wk = (const float*)d_in[2];
  const float* Wv = (const float*)d_in[3];
  const float* Wo = (const float*)d_in[4];
  const float* bo = (const float*)d_in[5];
  float* out = (float*)d_out;

  const size_t tsz = (size_t)16 * 4096 * 64;  // B*N*INNER elems
  unsigned short* qws = (unsigned short*)d_ws;
  unsigned short* kws = qws + tsz;
  unsigned short* vws = kws + tsz;
  unsigned short* ows = vws + tsz;
  unsigned short* wtq = ows + tsz;
  unsigned short* wtk = wtq + 512 * 512;
  unsigned short* wtv = wtk + 512 * 512;
  unsigned short* wto = wtv + 512 * 512;
  unsigned short* xb = wto + 512 * 512;  // x as bf16, [8192,512]

  prep_kernel<<<dim3(16, 16, 12), 256, 0, stream>>>(Wq, Wk, Wv, Wo, x, wtq,
                                                    wtk, wtv, wto, xb);
  qkv_fused_kernel<<<dim3(64, 16), 256, 0, stream>>>(xb, wtq, wtk, wtv, qws,
                                                     kws, vws);
  flash_kernel<<<dim3(16, 32), 256, 0, stream>>>(qws, kws, vws, ows);
  out_proj_kernel<<<dim3(128, 8), 256, 0, stream>>>(ows, wto, bo, out);
}

// Round 15
// 192.731 us; speedup vs baseline: 1.1117x; 1.1117x over previous
//
#include <hip/hip_runtime.h>
#include <hip/hip_bf16.h>

// Problem: B=2, N=4096, QD=512, HEADS=8, DIM_HEAD=64, INNER=512
// softmax scale 1/8 AND log2(e) folded into Q: P = exp2(S').
//
// FINAL configuration (session best, R13 = 192.7 us):
//   prep (W^T+bf16, x->bf16) -> fused QKV (all-DMA dbuf BK=64)
//   -> flash R7 (16 waves/CU, single-buffered K/V, reg prefetch)
//   -> out_proj (all-DMA dbuf BK=64).
// Measured plateau: flash 82% combined MFMA+VALU issue (m114-style two-pipe
// ceiling); projections overhead-bound (~97 us across 4 distinct designs).

typedef __attribute__((ext_vector_type(8))) short short8;
typedef __attribute__((ext_vector_type(4))) float floatx4;

#define MFMA16(a, b, c) __builtin_amdgcn_mfma_f32_16x16x32_bf16((a), (b), (c), 0, 0, 0)

#if __has_builtin(__builtin_amdgcn_exp2f)
#define EXP2(x) __builtin_amdgcn_exp2f(x)
#else
#define EXP2(x) exp2f(x)
#endif

// (1/8) * log2(e)
#define QSCALE 0.18033688011112042f

// fp32 -> bf16 (round-to-nearest-even)
static __device__ __forceinline__ unsigned short f2b(float f) {
  unsigned int u = __float_as_uint(f);
  u += 0x7FFFu + ((u >> 16) & 1u);
  return (unsigned short)(u >> 16);
}

// packed pair fp32 -> 2x bf16 in one u32
static __device__ __forceinline__ unsigned int pkb(float a, float b) {
  float2 t{a, b};
  __hip_bfloat162 h = __float22bfloat162_rn(t);
  union { __hip_bfloat162 h2; unsigned int u; } cv;
  cv.h2 = h;
  return cv.u;
}

// async global->LDS DMA: 16 B/lane; dest = wave-uniform base + lane*16.
static __device__ __forceinline__ void dma16(const unsigned short* g,
                                             unsigned short* l) {
  __builtin_amdgcn_global_load_lds(
      (const __attribute__((address_space(1))) unsigned int*)g,
      (__attribute__((address_space(3))) unsigned int*)l, 16, 0, 0);
}

// ---------------------------------------------------------------------------
// Kernel 0: prep — z 0..3: W transpose+bf16; z 4..11: x->bf16 slabs.
// ---------------------------------------------------------------------------
__global__ __launch_bounds__(256) void prep_kernel(
    const float* __restrict__ Wq, const float* __restrict__ Wk,
    const float* __restrict__ Wv, const float* __restrict__ Wo,
    const float* __restrict__ x, unsigned short* __restrict__ wtq,
    unsigned short* __restrict__ wtk, unsigned short* __restrict__ wtv,
    unsigned short* __restrict__ wto, unsigned short* __restrict__ xb) {
  const int z = blockIdx.z;
  const int tid = threadIdx.x;
  if (z >= 4) {
    const int bid = (z - 4) * 256 + blockIdx.y * 16 + blockIdx.x;
    const int idx = (bid * 256 + tid) * 8;
    const float4 a = *(const float4*)(x + idx);
    const float4 b = *(const float4*)(x + idx + 4);
    unsigned int u[4] = {pkb(a.x, a.y), pkb(a.z, a.w), pkb(b.x, b.y),
                         pkb(b.z, b.w)};
    *(short8*)(xb + idx) = *(short8*)u;
    return;
  }
  const float* __restrict__ W = (z == 0) ? Wq : (z == 1) ? Wk : (z == 2) ? Wv : Wo;
  unsigned short* __restrict__ T = (z == 0) ? wtq : (z == 1) ? wtk : (z == 2) ? wtv : wto;
  const int k0 = blockIdx.x * 32, c0 = blockIdx.y * 32;
  __shared__ float Ts[32][33];
  const int r = tid >> 3, cc = (tid & 7) * 4;
  const float4 v = *(const float4*)(W + (k0 + r) * 512 + c0 + cc);
  Ts[r][cc] = v.x; Ts[r][cc + 1] = v.y; Ts[r][cc + 2] = v.z; Ts[r][cc + 3] = v.w;
  __syncthreads();
  const unsigned long long uu =
      (unsigned long long)pkb(Ts[cc][r], Ts[cc + 1][r]) |
      ((unsigned long long)pkb(Ts[cc + 2][r], Ts[cc + 3][r]) << 32);
  *(unsigned long long*)(T + (c0 + r) * 512 + k0 + cc) = uu;
}

// ---------------------------------------------------------------------------
// Kernel 1: fused QKV — all-DMA double-buffered single-barrier pipeline.
// M=128 x N=32 per z, BK=64 (8 ksteps).  Dense 128B rows, XOR chunk swizzle.
// ---------------------------------------------------------------------------
__global__ __launch_bounds__(256) void qkv_fused_kernel(
    const unsigned short* __restrict__ xb, const unsigned short* __restrict__ wtq,
    const unsigned short* __restrict__ wtk,
    const unsigned short* __restrict__ wtv, unsigned short* __restrict__ qo,
    unsigned short* __restrict__ ko, unsigned short* __restrict__ vo) {
  const int m0 = blockIdx.x * 128;  // 64
  const int c0 = blockIdx.y * 32;   // 16
  __shared__ __align__(16) unsigned short As[2][128 * 64];    // 32 KB
  __shared__ __align__(16) unsigned short Bs[2][3][32 * 64];  // 24 KB
  const int tid = threadIdx.x;
  const int lane = tid & 63, w = tid >> 6;
  const int i = lane & 15, q = lane >> 4;
  const int sl = i & 7;
  const int dr = lane >> 3, dc = lane & 7;
  const int sch = (dc ^ dr) * 8;
  const unsigned short* ag = xb + (m0 + w * 32 + dr) * 512 + sch;
  const unsigned short* bg[3];
  bg[0] = wtq + (c0 + w * 8 + dr) * 512 + sch;
  bg[1] = wtk + (c0 + w * 8 + dr) * 512 + sch;
  bg[2] = wtv + (c0 + w * 8 + dr) * 512 + sch;

  floatx4 acc[3][2][2] = {};

#pragma unroll
  for (int p = 0; p < 4; ++p) dma16(ag + p * 8 * 512, &As[0][(w * 32 + p * 8) * 64]);
#pragma unroll
  for (int z = 0; z < 3; ++z) dma16(bg[z], &Bs[0][z][(w * 8) * 64]);
  __syncthreads();

  int buf = 0;
  for (int ks = 0; ks < 8; ++ks) {
    if (ks < 7) {
      const int k1 = (ks + 1) * 64;
#pragma unroll
      for (int p = 0; p < 4; ++p)
        dma16(ag + p * 8 * 512 + k1, &As[buf ^ 1][(w * 32 + p * 8) * 64]);
#pragma unroll
      for (int z = 0; z < 3; ++z)
        dma16(bg[z] + k1, &Bs[buf ^ 1][z][(w * 8) * 64]);
    }
#pragma unroll
    for (int kc = 0; kc < 2; ++kc) {
      short8 af[2];
#pragma unroll
      for (int t = 0; t < 2; ++t)
        af[t] = *(const short8*)&As[buf][(w * 32 + t * 16 + i) * 64 +
                                        (((kc * 4 + q) ^ sl) * 8)];
#pragma unroll
      for (int z = 0; z < 3; ++z)
#pragma unroll
        for (int g = 0; g < 2; ++g) {
          const short8 bf = *(const short8*)&Bs[buf][z][(g * 16 + i) * 64 +
                                                        (((kc * 4 + q) ^ sl) * 8)];
#pragma unroll
          for (int t = 0; t < 2; ++t)
            acc[z][t][g] = MFMA16(af[t], bf, acc[z][t][g]);
        }
    }
    __syncthreads();
    buf ^= 1;
  }
#pragma unroll
  for (int z = 0; z < 3; ++z)
#pragma unroll
    for (int t = 0; t < 2; ++t)
#pragma unroll
      for (int g = 0; g < 2; ++g) {
        const int col = c0 + g * 16 + i;
        const int h = col >> 6, d = col & 63;
        const int row0 = m0 + w * 32 + t * 16 + q * 4;
        const int b = row0 >> 12;
        const int n0 = row0 & 4095;
        if (z == 2) {
          unsigned int* dst =
              (unsigned int*)&vo[(((b * 8 + h) * 64 + d) << 12) + n0];
          dst[0] = pkb(acc[z][t][g][0], acc[z][t][g][1]);
          dst[1] = pkb(acc[z][t][g][2], acc[z][t][g][3]);
        } else {
          unsigned short* dst = (z == 0) ? qo : ko;
          const float sc = (z == 0) ? QSCALE : 1.0f;
#pragma unroll
          for (int r = 0; r < 4; ++r)
            dst[(((b * 8 + h) << 12) + (n0 + r)) * 64 + d] =
                f2b(acc[z][t][g][r] * sc);
        }
      }
}

// ---------------------------------------------------------------------------
// Kernel 2: flash attention — VERBATIM R7 (95.4–96.9 us, verified 5x).
// 512 threads = 8 waves = 4 row-tiles x 2 key groups; 16 waves/CU; bh in low
// grid bits (per-XCD L2 holds ~2 bh of K/V); single-buffered K/V with
// register prefetch; XOR-swizzled LDS; ones-column MFMA row-sum.
// ---------------------------------------------------------------------------
__global__ __launch_bounds__(512, 4) void flash_kernel(
    const unsigned short* __restrict__ Q, const unsigned short* __restrict__ K,
    const unsigned short* __restrict__ Vt, unsigned short* __restrict__ O) {
  const int bh = blockIdx.x;        // 16
  const int m0 = blockIdx.y * 128;  // 32
  const int tid = threadIdx.x;
  const int lane = tid & 63, w = tid >> 6;
  const int i = lane & 15, q = lane >> 4;
  const int rt = w & 3;   // row tile (32 rows)
  const int kg = w >> 2;  // key group (2048 keys)
  const unsigned short* qp = Q + bh * (4096 * 64);
  const unsigned short* kp = K + bh * (4096 * 64);
  const unsigned short* vp = Vt + bh * (64 * 4096);

  __shared__ __align__(16) unsigned short SM[32768];  // 64 KB
  unsigned short* Ks = SM + kg * 4096;          // [64 rows][64], swizzled
  unsigned short* Vs = SM + 8192 + kg * 4096;   // [64 rows][64], swizzled
  unsigned short* pw = SM + 16384 + w * 2048;   // per-wave P [32][64], swizzled

  const int srow = (tid & 255) >> 3;  // 0..31 (and +32)
  const int c0s = tid & 7;            // source 16B chunk
  const int sw8 = (c0s ^ (srow & 7)) * 8;
  const unsigned short* kgp = kp + (kg * 2048 + srow) * 64 + c0s * 8;
  const unsigned short* vgp = vp + srow * 4096 + kg * 2048 + c0s * 8;

  short8 qf[2][2];
#pragma unroll
  for (int t = 0; t < 2; ++t)
#pragma unroll
    for (int kc = 0; kc < 2; ++kc)
      qf[t][kc] = *(const short8*)(qp + (m0 + rt * 32 + t * 16 + i) * 64 +
                                   kc * 32 + q * 8);

  floatx4 accO[2][4] = {};
  floatx4 accL[2] = {};
  short8 ones;
  {
    const short ov = (i == 0) ? (short)0x3F80 : (short)0;  // bf16 1.0, col 0
#pragma unroll
    for (int j = 0; j < 8; ++j) ones[j] = ov;
  }
  const floatx4 zf = {0.f, 0.f, 0.f, 0.f};
  const int sl = i & 7;

  *(short8*)&Ks[srow * 64 + sw8] = *(const short8*)(kgp);
  *(short8*)&Ks[(srow + 32) * 64 + sw8] = *(const short8*)(kgp + 32 * 64);
  *(short8*)&Vs[srow * 64 + sw8] = *(const short8*)(vgp);
  *(short8*)&Vs[(srow + 32) * 64 + sw8] = *(const short8*)(vgp + 32 * 4096);
  __syncthreads();

  for (int jt = 0; jt < 32; ++jt) {
    short8 kn0, kn1, vn0, vn1;
    if (jt < 31) {
      kn0 = *(const short8*)(kgp + (jt + 1) * 4096);
      kn1 = *(const short8*)(kgp + (jt + 1) * 4096 + 32 * 64);
      vn0 = *(const short8*)(vgp + (jt + 1) * 64);
      vn1 = *(const short8*)(vgp + (jt + 1) * 64 + 32 * 4096);
    }
#pragma unroll
    for (int g = 0; g < 4; ++g) {
      const short8 kf0 = *(const short8*)(&Ks[(g * 16 + i) * 64 + (q ^ sl) * 8]);
      const short8 kf1 =
          *(const short8*)(&Ks[(g * 16 + i) * 64 + ((4 + q) ^ sl) * 8]);
#pragma unroll
      for (int t = 0; t < 2; ++t) {
        floatx4 s = MFMA16(kf0, qf[t][0], zf);
        s = MFMA16(kf1, qf[t][1], s);
        const float e0 = EXP2(s[0]), e1 = EXP2(s[1]);
        const float e2 = EXP2(s[2]), e3 = EXP2(s[3]);
        *(unsigned long long*)&pw[(t * 16 + i) * 64 +
                                  (((2 * g + (q >> 1)) ^ sl) * 8) +
                                  (q & 1) * 4] =
            (unsigned long long)pkb(e0, e1) |
            ((unsigned long long)pkb(e2, e3) << 32);
      }
    }
    short8 pf[2][2];
#pragma unroll
    for (int t = 0; t < 2; ++t) {
      pf[t][0] = *(const short8*)(pw + (t * 16 + i) * 64 + (q ^ sl) * 8);
      pf[t][1] = *(const short8*)(pw + (t * 16 + i) * 64 + ((4 + q) ^ sl) * 8);
      accL[t] = MFMA16(pf[t][0], ones, accL[t]);
      accL[t] = MFMA16(pf[t][1], ones, accL[t]);
    }
#pragma unroll
    for (int dg = 0; dg < 4; ++dg) {
      const short8 vf0 =
          *(const short8*)(&Vs[(dg * 16 + i) * 64 + (q ^ sl) * 8]);
      const short8 vf1 =
          *(const short8*)(&Vs[(dg * 16 + i) * 64 + ((4 + q) ^ sl) * 8]);
#pragma unroll
      for (int t = 0; t < 2; ++t) {
        accO[t][dg] = MFMA16(pf[t][0], vf0, accO[t][dg]);
        accO[t][dg] = MFMA16(pf[t][1], vf1, accO[t][dg]);
      }
    }
    __syncthreads();
    if (jt < 31) {
      *(short8*)&Ks[srow * 64 + sw8] = kn0;
      *(short8*)&Ks[(srow + 32) * 64 + sw8] = kn1;
      *(short8*)&Vs[srow * 64 + sw8] = vn0;
      *(short8*)&Vs[(srow + 32) * 64 + sw8] = vn1;
    }
    __syncthreads();
  }

  float* MB = (float*)SM;
  if (kg == 1) {
    float* dst = MB + (rt * 64 + lane) * 40;
#pragma unroll
    for (int t = 0; t < 2; ++t) {
#pragma unroll
      for (int dg = 0; dg < 4; ++dg)
#pragma unroll
        for (int r = 0; r < 4; ++r) dst[t * 16 + dg * 4 + r] = accO[t][dg][r];
#pragma unroll
      for (int r = 0; r < 4; ++r) dst[32 + t * 4 + r] = accL[t][r];
    }
  }
  __syncthreads();
  if (kg == 1) return;
  {
    const float* src = MB + (rt * 64 + lane) * 40;
#pragma unroll
    for (int t = 0; t < 2; ++t) {
#pragma unroll
      for (int dg = 0; dg < 4; ++dg)
#pragma unroll
        for (int r = 0; r < 4; ++r) accO[t][dg][r] += src[t * 16 + dg * 4 + r];
#pragma unroll
      for (int r = 0; r < 4; ++r) accL[t][r] += src[32 + t * 4 + r];
    }
  }

  const int b = bh >> 3, h = bh & 7;
#pragma unroll
  for (int t = 0; t < 2; ++t) {
    float inv[4];
#pragma unroll
    for (int r = 0; r < 4; ++r) {
      const float l = __shfl(accL[t][r], lane & 48, 64);
      inv[r] = 1.0f / l;
    }
#pragma unroll
    for (int dg = 0; dg < 4; ++dg)
#pragma unroll
      for (int r = 0; r < 4; ++r) {
        const int n = m0 + rt * 32 + t * 16 + q * 4 + r;
        const int col = h * 64 + dg * 16 + i;
        O[((b << 12) + n) * 512 + col] = f2b(accO[t][dg][r] * inv[r]);
      }
  }
}

// ---------------------------------------------------------------------------
// Kernel 3: out projection — all-DMA dbuf single-barrier, 64x64, BK=64.
// ---------------------------------------------------------------------------
__global__ __launch_bounds__(256) void out_proj_kernel(
    const unsigned short* __restrict__ A, const unsigned short* __restrict__ wto,
    const float* __restrict__ bo, float* __restrict__ out) {
  const int m0 = blockIdx.x * 64, c0 = blockIdx.y * 64;
  __shared__ __align__(16) unsigned short As[2][64 * 64];  // 16 KB
  __shared__ __align__(16) unsigned short Bs[2][64 * 64];  // 16 KB
  const int tid = threadIdx.x;
  const int lane = tid & 63, w = tid >> 6;
  const int i = lane & 15, q = lane >> 4;
  const int wy = w >> 1, wx = w & 1;
  const int sl = i & 7;
  const int dr = lane >> 3, dc = lane & 7;
  const int sch = (dc ^ dr) * 8;
  const unsigned short* ag = A + (m0 + w * 16 + dr) * 512 + sch;
  const unsigned short* bg = wto + (c0 + w * 16 + dr) * 512 + sch;

  floatx4 acc[2][2] = {};
#pragma unroll
  for (int p = 0; p < 2; ++p) {
    dma16(ag + p * 8 * 512, &As[0][(w * 16 + p * 8) * 64]);
    dma16(bg + p * 8 * 512, &Bs[0][(w * 16 + p * 8) * 64]);
  }
  __syncthreads();

  int buf = 0;
  for (int ks = 0; ks < 8; ++ks) {
    if (ks < 7) {
      const int k1 = (ks + 1) * 64;
#pragma unroll
      for (int p = 0; p < 2; ++p) {
        dma16(ag + p * 8 * 512 + k1, &As[buf ^ 1][(w * 16 + p * 8) * 64]);
        dma16(bg + p * 8 * 512 + k1, &Bs[buf ^ 1][(w * 16 + p * 8) * 64]);
      }
    }
#pragma unroll
    for (int kc = 0; kc < 2; ++kc) {
      short8 af[2], bfr[2];
#pragma unroll
      for (int t = 0; t < 2; ++t)
        af[t] = *(const short8*)&As[buf][(wy * 32 + t * 16 + i) * 64 +
                                        (((kc * 4 + q) ^ sl) * 8)];
#pragma unroll
      for (int g = 0; g < 2; ++g)
        bfr[g] = *(const short8*)&Bs[buf][(wx * 32 + g * 16 + i) * 64 +
                                          (((kc * 4 + q) ^ sl) * 8)];
#pragma unroll
      for (int t = 0; t < 2; ++t)
#pragma unroll
        for (int g = 0; g < 2; ++g) acc[t][g] = MFMA16(af[t], bfr[g], acc[t][g]);
    }
    __syncthreads();
    buf ^= 1;
  }
#pragma unroll
  for (int t = 0; t < 2; ++t)
#pragma unroll
    for (int g = 0; g < 2; ++g) {
      const int col = c0 + wx * 32 + g * 16 + i;
      const float bias = bo[col];
#pragma unroll
      for (int r = 0; r < 4; ++r) {
        const int row = m0 + wy * 32 + t * 16 + q * 4 + r;
        out[row * 512 + col] = acc[t][g][r] + bias;
      }
    }
}

// ---------------------------------------------------------------------------
extern "C" void kernel_launch(void* const* d_in, const int* in_sizes, int n_in,
                              void* d_out, int out_size, void* d_ws,
                              size_t ws_size, hipStream_t stream) {
  const float* x = (const float*)d_in[0];
  const float* Wq = (const float*)d_in[1];
  const float* Wk = (const float*)d_in[2];
  const float* Wv = (const float*)d_in[3];
  const float* Wo = (const float*)d_in[4];
  const float* bo = (const float*)d_in[5];
  float* out = (float*)d_out;

  const size_t tsz = (size_t)16 * 4096 * 64;  // B*N*INNER elems
  unsigned short* qws = (unsigned short*)d_ws;
  unsigned short* kws = qws + tsz;
  unsigned short* vws = kws + tsz;
  unsigned short* ows = vws + tsz;
  unsigned short* wtq = ows + tsz;
  unsigned short* wtk = wtq + 512 * 512;
  unsigned short* wtv = wtk + 512 * 512;
  unsigned short* wto = wtv + 512 * 512;
  unsigned short* xb = wto + 512 * 512;  // x as bf16, [8192,512]

  prep_kernel<<<dim3(16, 16, 12), 256, 0, stream>>>(Wq, Wk, Wv, Wo, x, wtq,
                                                    wtk, wtv, wto, xb);
  qkv_fused_kernel<<<dim3(64, 16), 256, 0, stream>>>(xb, wtq, wtk, wtv, qws,
                                                     kws, vws);
  flash_kernel<<<dim3(16, 32), 512, 0, stream>>>(qws, kws, vws, ows);
  out_proj_kernel<<<dim3(128, 8), 256, 0, stream>>>(ows, wto, bo, out);
}